// Round 5
// baseline (341.912 us; speedup 1.0000x reference)
//
#include <hip/hip_runtime.h>

// Problem constants
#define N_NODES 25000
#define N_EDGES 200000
// MUL=16, NUM_RADIAL=8, HIDDEN=64, WNUMEL=1024
// PATH_ALPHA=1/sqrt(32), INV_SQRT3=1/sqrt(3), scales folded into B-fragments.

constexpr int ET = 16;      // edges per tile
constexpr int NT = 10;      // tiles per block   (round 5: was 25)
constexpr int NBLK = 1250;  // 1250*10*16 = 200000 edges exactly (round 5: was 500)

typedef __attribute__((ext_vector_type(8))) _Float16 half8;  // 8 f16 (4 VGPR)
typedef __attribute__((ext_vector_type(4))) float float4v;   // 4 fp32

// ---------------- self-connection (round-1 verified version) ----------------
__global__ __launch_bounds__(256) void sc_kernel(const float* __restrict__ x,
                                                 const float* __restrict__ L0,
                                                 const float* __restrict__ L1,
                                                 float* __restrict__ out) {
    int idx = blockIdx.x * 256 + threadIdx.x;
    if (idx >= N_NODES * 64) return;
    int n = idx >> 6, j = idx & 63;
    const float* xr = x + n * 64;
    float s = 0.f;
    if (j < 16) {
        int v = j;
        #pragma unroll
        for (int u = 0; u < 16; ++u) s = fmaf(xr[u], L0[u * 16 + v], s);
    } else {
        int v = (j - 16) / 3, k = (j - 16) % 3;
        #pragma unroll
        for (int u = 0; u < 16; ++u) s = fmaf(xr[16 + u * 3 + k], L1[u * 16 + v], s);
    }
    out[idx] = 0.25f * s;  // 1/sqrt(MUL)
}

// ---------------- edge kernel: f16 MFMA GEMM + fused contraction ----------------
// Round-4 verified structure; round 5 changes ONLY the grid/tile split.
__global__ __launch_bounds__(256, 2) void edge_kernel(
    const float* __restrict__ x, const float* __restrict__ edge_attr,
    const float* __restrict__ edge_length, const int* __restrict__ edge_src,
    const int* __restrict__ edge_dst, const float* __restrict__ W1,
    const float* __restrict__ W2, float* __restrict__ out) {

    const int t = threadIdx.x;
    const int prog = t >> 6;          // wave id == which 16x16-block family of w
    const int qm = t & 15;            // MFMA n / v / m index
    const int quad = (t >> 4) & 3;    // lane quad

    __shared__ __attribute__((aligned(16))) float lds_h[16 * 72];   // fp32 h, row stride 72
    __shared__ __attribute__((aligned(16))) float lds_xj[16 * 68];  // gathered x[src], stride 68
    __shared__ __attribute__((aligned(16))) float lds_b1[16 * 68];  // b1[e][u]=sum_k xj1[u,k]sh1[k]
    __shared__ __attribute__((aligned(16))) float lds_xt[48 * 20];  // xj1 transposed: row e*3+k, [u]
    __shared__ __attribute__((aligned(16))) float lds_w1t[64 * 8];  // W1 transposed [c][r]
    __shared__ __attribute__((aligned(16))) float lds_sh[16 * 4];
    __shared__ __attribute__((aligned(16))) float lds_len[16];
    __shared__ __attribute__((aligned(16))) int   lds_dst[16];

    // ---- persistent B fragments: W2 block `prog`, pre-scaled, f16 ----
    // B-frag layout (16x16x32): lane holds B[k = kf*32 + quad*8 + j][n = qm]
    half8 bfr[16][2];
    {
        float scale = 0.0220970869f;                  // (1/sqrt(64)) * (1/sqrt(32))
        if (prog == 1) scale *= 0.5773502692f;        // INV_SQRT3 folded
        const int kr = quad * 8;
        const int col0 = prog * 256 + qm;
        #pragma unroll
        for (int u = 0; u < 16; ++u) {
            #pragma unroll
            for (int kf = 0; kf < 2; ++kf) {
                half8 f;
                #pragma unroll
                for (int j = 0; j < 8; ++j) {
                    const int k = kf * 32 + kr + j;
                    f[j] = (_Float16)(W2[k * 1024 + col0 + u * 16] * scale);
                }
                bfr[u][kf] = f;
            }
        }
    }
    // W1 -> LDS transposed [c][r]
    for (int i = t; i < 512; i += 256) {
        const int r = i >> 6, c = i & 63;
        lds_w1t[c * 8 + r] = W1[i];
    }

    for (int tl = 0; tl < NT; ++tl) {
        const int e0 = (blockIdx.x * NT + tl) * ET;
        __syncthreads();   // protect LDS vs previous tile's epilogue readers

        // ---- phase 1: meta + xj gather ----
        if (t < 16) {
            lds_dst[t] = edge_dst[e0 + t];
            lds_len[t] = edge_length[e0 + t];
            const float4v ea = *(const float4v*)(edge_attr + 4 * (e0 + t));
            lds_sh[t * 4 + 0] = ea[0]; lds_sh[t * 4 + 1] = ea[1];
            lds_sh[t * 4 + 2] = ea[2]; lds_sh[t * 4 + 3] = ea[3];
        }
        {
            const int e_loc = prog * 4 + quad;            // wave loads 4 edges
            const int src = edge_src[e0 + e_loc];
            const float4v xv = *(const float4v*)(x + src * 64 + qm * 4);
            *(float4v*)(&lds_xj[e_loc * 68 + qm * 4]) = xv;
        }
        __syncthreads();

        // ---- phase 2a: per-(e,u) coefficients ----
        {
            const int e = t & 15, u = t >> 4;
            const float s1x = lds_sh[e * 4 + 1];
            const float s1y = lds_sh[e * 4 + 2];
            const float s1z = lds_sh[e * 4 + 3];
            const float x0 = lds_xj[e * 68 + 16 + 3 * u];
            const float x1 = lds_xj[e * 68 + 17 + 3 * u];
            const float x2 = lds_xj[e * 68 + 18 + 3 * u];
            lds_b1[e * 68 + u] = fmaf(x0, s1x, fmaf(x1, s1y, x2 * s1z));
            lds_xt[(e * 3 + 0) * 20 + u] = x0;
            lds_xt[(e * 3 + 1) * 20 + u] = x1;
            lds_xt[(e * 3 + 2) * 20 + u] = x2;
        }
        // ---- phase 2b: h = silu(radial @ W1 / sqrt(8)) -> fp32 LDS ----
        {
            const int e = t & 15, c0 = (t >> 4) * 4;
            const float len = lds_len[e];
            float rad[8];
            #pragma unroll
            for (int r = 0; r < 8; ++r) {
                const float d = len - 0.7142857143f * (float)r;
                rad[r] = __expf(-0.5f * d * d);
            }
            float4v hv;
            #pragma unroll
            for (int i = 0; i < 4; ++i) {
                const float4v wA = *(const float4v*)(&lds_w1t[(c0 + i) * 8]);
                const float4v wB = *(const float4v*)(&lds_w1t[(c0 + i) * 8 + 4]);
                float s = rad[0] * wA[0] + rad[1] * wA[1] + rad[2] * wA[2] + rad[3] * wA[3]
                        + rad[4] * wB[0] + rad[5] * wB[1] + rad[6] * wB[2] + rad[7] * wB[3];
                s *= 0.3535533906f;
                hv[i] = s / (1.f + __expf(-s));
            }
            *(float4v*)(&lds_h[e * 72 + c0]) = hv;
        }
        __syncthreads();

        // ---- phase 3: build A fragments (f16 hi/lo from fp32 LDS) ----
        // A-frag: lane holds h[m=qm][k = kf*32 + quad*8 + j]
        const float* hrow = &lds_h[qm * 72];
        const float4v fa = *(const float4v*)(hrow + quad * 8);
        const float4v fb = *(const float4v*)(hrow + quad * 8 + 4);
        const float4v fc = *(const float4v*)(hrow + 32 + quad * 8);
        const float4v fd = *(const float4v*)(hrow + 32 + quad * 8 + 4);
        half8 ah0, al0, ah1, al1;
        #pragma unroll
        for (int j = 0; j < 4; ++j) {
            _Float16 hh;
            hh = (_Float16)fa[j]; ah0[j]     = hh; al0[j]     = (_Float16)(fa[j] - (float)hh);
            hh = (_Float16)fb[j]; ah0[4 + j] = hh; al0[4 + j] = (_Float16)(fb[j] - (float)hh);
            hh = (_Float16)fc[j]; ah1[j]     = hh; al1[j]     = (_Float16)(fc[j] - (float)hh);
            hh = (_Float16)fd[j]; ah1[4 + j] = hh; al1[4 + j] = (_Float16)(fd[j] - (float)hh);
        }
        // ---- MFMA (16 u-tiles, K=64, hi+lo A split) ----
        float4v acc[16];
        #pragma unroll
        for (int u = 0; u < 16; ++u) acc[u] = (float4v){0.f, 0.f, 0.f, 0.f};
        #pragma unroll
        for (int u = 0; u < 16; ++u) {
            acc[u] = __builtin_amdgcn_mfma_f32_16x16x32_f16(ah0, bfr[u][0], acc[u], 0, 0, 0);
            acc[u] = __builtin_amdgcn_mfma_f32_16x16x32_f16(al0, bfr[u][0], acc[u], 0, 0, 0);
            acc[u] = __builtin_amdgcn_mfma_f32_16x16x32_f16(ah1, bfr[u][1], acc[u], 0, 0, 0);
            acc[u] = __builtin_amdgcn_mfma_f32_16x16x32_f16(al1, bfr[u][1], acc[u], 0, 0, 0);
        }
        // C layout: col v = qm, row e = quad*4 + r  (r = reg)

        // ---- epilogue: u-contraction + DIRECT per-prog atomics ----
        if (prog == 0 || prog == 2) {
            #pragma unroll
            for (int r = 0; r < 4; ++r) {
                const int er = quad * 4 + r;
                const float4v* b = (const float4v*)&lds_xj[er * 68];   // xj0 rows
                float s = 0.f;
                #pragma unroll
                for (int c4 = 0; c4 < 4; ++c4) {
                    const float4v p = b[c4];
                    s = fmaf(p[0], acc[c4 * 4 + 0][r], s);
                    s = fmaf(p[1], acc[c4 * 4 + 1][r], s);
                    s = fmaf(p[2], acc[c4 * 4 + 2][r], s);
                    s = fmaf(p[3], acc[c4 * 4 + 3][r], s);
                }
                float* op = out + lds_dst[er] * 64;
                if (prog == 0) {
                    // m0 term 1: sum_u xj0*sh0 * w0[u,v]
                    atomicAdd(op + qm, s * lds_sh[er * 4]);
                } else {
                    // m1 term 1: (sum_u xj0*w2[u,v]) * sh1[k]
                    #pragma unroll
                    for (int k = 0; k < 3; ++k)
                        atomicAdd(op + 16 + qm * 3 + k, s * lds_sh[er * 4 + 1 + k]);
                }
            }
        } else if (prog == 1) {
            // m0 term 2: sum_u b1[u]*w1[u,v]  (INV_SQRT3 folded into bfr)
            #pragma unroll
            for (int r = 0; r < 4; ++r) {
                const int er = quad * 4 + r;
                const float4v* b = (const float4v*)&lds_b1[er * 68];
                float s = 0.f;
                #pragma unroll
                for (int c4 = 0; c4 < 4; ++c4) {
                    const float4v p = b[c4];
                    s = fmaf(p[0], acc[c4 * 4 + 0][r], s);
                    s = fmaf(p[1], acc[c4 * 4 + 1][r], s);
                    s = fmaf(p[2], acc[c4 * 4 + 2][r], s);
                    s = fmaf(p[3], acc[c4 * 4 + 3][r], s);
                }
                atomicAdd(out + lds_dst[er] * 64 + qm, s);
            }
        } else {
            // m1 term 2: sh0 * sum_u xj1[u,k]*w3[u,v]
            #pragma unroll
            for (int r = 0; r < 4; ++r) {
                const int er = quad * 4 + r;
                const float sh0 = lds_sh[er * 4];
                float* op = out + lds_dst[er] * 64;
                #pragma unroll
                for (int k = 0; k < 3; ++k) {
                    const float4v* b = (const float4v*)&lds_xt[(er * 3 + k) * 20];
                    float s = 0.f;
                    #pragma unroll
                    for (int c4 = 0; c4 < 4; ++c4) {
                        const float4v p = b[c4];
                        s = fmaf(p[0], acc[c4 * 4 + 0][r], s);
                        s = fmaf(p[1], acc[c4 * 4 + 1][r], s);
                        s = fmaf(p[2], acc[c4 * 4 + 2][r], s);
                        s = fmaf(p[3], acc[c4 * 4 + 3][r], s);
                    }
                    atomicAdd(op + 16 + qm * 3 + k, s * sh0);
                }
            }
        }
        // no barrier needed here: next-iteration top barrier orders epilogue
        // LDS reads before phase-1 overwrites
    }
}

extern "C" void kernel_launch(void* const* d_in, const int* in_sizes, int n_in,
                              void* d_out, int out_size, void* d_ws, size_t ws_size,
                              hipStream_t stream) {
    const float* x           = (const float*)d_in[0];
    const float* edge_attr   = (const float*)d_in[1];
    const float* edge_length = (const float*)d_in[2];
    const int*   edge_src    = (const int*)d_in[3];
    const int*   edge_dst    = (const int*)d_in[4];
    const float* W1          = (const float*)d_in[5];
    const float* W2          = (const float*)d_in[6];
    const float* L0          = (const float*)d_in[7];
    const float* L1          = (const float*)d_in[8];
    float* out = (float*)d_out;

    sc_kernel<<<(N_NODES * 64 + 255) / 256, 256, 0, stream>>>(x, L0, L1, out);
    edge_kernel<<<NBLK, 256, 0, stream>>>(
        x, edge_attr, edge_length, edge_src, edge_dst, W1, W2, out);
}

// Round 6
// 301.681 us; speedup vs baseline: 1.1334x; 1.1334x over previous
//
#include <hip/hip_runtime.h>

// Problem constants
#define N_NODES 25000
#define N_EDGES 200000
// MUL=16, NUM_RADIAL=8, HIDDEN=64, WNUMEL=1024
// PATH_ALPHA=1/sqrt(32), INV_SQRT3=1/sqrt(3), scales folded into B-fragments.

constexpr int ET = 16;      // edges per tile
constexpr int NT = 10;      // tiles per block
constexpr int NBLK = 1250;  // 1250*10*16 = 200000 edges exactly

typedef __attribute__((ext_vector_type(8))) _Float16 half8;  // 8 f16 (4 VGPR)
typedef __attribute__((ext_vector_type(4))) float float4v;   // 4 fp32

// ---------------- self-connection (round-1 verified version) ----------------
__global__ __launch_bounds__(256) void sc_kernel(const float* __restrict__ x,
                                                 const float* __restrict__ L0,
                                                 const float* __restrict__ L1,
                                                 float* __restrict__ out) {
    int idx = blockIdx.x * 256 + threadIdx.x;
    if (idx >= N_NODES * 64) return;
    int n = idx >> 6, j = idx & 63;
    const float* xr = x + n * 64;
    float s = 0.f;
    if (j < 16) {
        int v = j;
        #pragma unroll
        for (int u = 0; u < 16; ++u) s = fmaf(xr[u], L0[u * 16 + v], s);
    } else {
        int v = (j - 16) / 3, k = (j - 16) % 3;
        #pragma unroll
        for (int u = 0; u < 16; ++u) s = fmaf(xr[16 + u * 3 + k], L1[u * 16 + v], s);
    }
    out[idx] = 0.25f * s;  // 1/sqrt(MUL)
}

// ---------------- edge kernel: 8-wave, u-streamed MFMA, low-register ----------------
// Round 6: 512 threads/block. Wave w: prog = w>>1, u-half = w&1 (8 u values).
// bfr = 64 VGPR (half of round 5), acc streamed (4 regs, was 64 AGPR).
// fp32 LDS exchange combines u-halves + prog pairs -> 1 atomic per output elem.
__global__ __launch_bounds__(512, 4) void edge_kernel(
    const float* __restrict__ x, const float* __restrict__ edge_attr,
    const float* __restrict__ edge_length, const int* __restrict__ edge_src,
    const int* __restrict__ edge_dst, const float* __restrict__ W1,
    const float* __restrict__ W2, float* __restrict__ out) {

    const int t = threadIdx.x;
    const int w = t >> 6;             // wave id 0..7
    const int prog = w >> 1;          // which 16x16-block family of w2
    const int uh = w & 1;             // u-half: u in [uh*8, uh*8+8)
    const int qm = t & 15;            // MFMA n / v / m index
    const int quad = (t >> 4) & 3;    // lane quad within wave

    __shared__ __attribute__((aligned(16))) float lds_h[16 * 72];   // fp32 h, row stride 72
    __shared__ __attribute__((aligned(16))) float lds_xj[16 * 68];  // gathered x[src], stride 68
    __shared__ __attribute__((aligned(16))) float lds_b1[16 * 68];  // b1[e][u]=sum_k xj1[u,k]sh1[k]
    __shared__ __attribute__((aligned(16))) float lds_xt[48 * 20];  // xj1^T: row e*3+k, [u]
    __shared__ __attribute__((aligned(16))) float lds_w1t[64 * 8];  // W1^T [c][r]
    __shared__ __attribute__((aligned(16))) float lds_sh[16 * 4];
    __shared__ __attribute__((aligned(16))) float lds_len[16];
    __shared__ __attribute__((aligned(16))) int   lds_dst[16];
    // exchange: waves 0..5 (progs 0,1,2 x uh): [w][e*17+v]; waves 6,7 (prog3): [e*51+v*3+k]
    __shared__ __attribute__((aligned(16))) float lds_xch[6 * 272 + 2 * 816];

    // ---- persistent B fragments: W2 block `prog`, u-half `uh`, pre-scaled f16 ----
    // B-frag layout (16x16x32): lane holds B[k = kf*32 + quad*8 + j][n = qm]
    half8 bfr[8][2];
    {
        float scale = 0.0220970869f;                  // (1/sqrt(64)) * (1/sqrt(32))
        if (prog == 1) scale *= 0.5773502692f;        // INV_SQRT3 folded
        const int kr = quad * 8;
        #pragma unroll
        for (int up = 0; up < 8; ++up) {
            const int col = prog * 256 + (uh * 8 + up) * 16 + qm;
            #pragma unroll
            for (int kf = 0; kf < 2; ++kf) {
                half8 f;
                #pragma unroll
                for (int j = 0; j < 8; ++j) {
                    const int k = kf * 32 + kr + j;
                    f[j] = (_Float16)(W2[k * 1024 + col] * scale);
                }
                bfr[up][kf] = f;
            }
        }
    }
    // W1 -> LDS transposed [c][r]
    for (int i = t; i < 512; i += 512) {
        const int r = i >> 6, c = i & 63;
        lds_w1t[c * 8 + r] = W1[i];
    }

    for (int tl = 0; tl < NT; ++tl) {
        const int e0 = (blockIdx.x * NT + tl) * ET;
        __syncthreads();   // orders prev-tile combine reads before re-staging

        // ---- phase 1: meta + xj gather (first 4 waves; round-5-verified code) ----
        if (t < 16) {
            lds_dst[t] = edge_dst[e0 + t];
            lds_len[t] = edge_length[e0 + t];
            const float4v ea = *(const float4v*)(edge_attr + 4 * (e0 + t));
            lds_sh[t * 4 + 0] = ea[0]; lds_sh[t * 4 + 1] = ea[1];
            lds_sh[t * 4 + 2] = ea[2]; lds_sh[t * 4 + 3] = ea[3];
        }
        if (t < 256) {
            const int e_loc = (t >> 6) * 4 + quad;        // 4 staging waves x 4 edges
            const int src = edge_src[e0 + e_loc];
            const float4v xv = *(const float4v*)(x + src * 64 + qm * 4);
            *(float4v*)(&lds_xj[e_loc * 68 + qm * 4]) = xv;
        }
        __syncthreads();

        if (t < 256) {
            // ---- phase 2a: per-(e,u) coefficients ----
            {
                const int e = t & 15, u = t >> 4;
                const float s1x = lds_sh[e * 4 + 1];
                const float s1y = lds_sh[e * 4 + 2];
                const float s1z = lds_sh[e * 4 + 3];
                const float x0 = lds_xj[e * 68 + 16 + 3 * u];
                const float x1 = lds_xj[e * 68 + 17 + 3 * u];
                const float x2 = lds_xj[e * 68 + 18 + 3 * u];
                lds_b1[e * 68 + u] = fmaf(x0, s1x, fmaf(x1, s1y, x2 * s1z));
                lds_xt[(e * 3 + 0) * 20 + u] = x0;
                lds_xt[(e * 3 + 1) * 20 + u] = x1;
                lds_xt[(e * 3 + 2) * 20 + u] = x2;
            }
            // ---- phase 2b: h = silu(radial @ W1 / sqrt(8)) -> fp32 LDS ----
            {
                const int e = t & 15, c0 = (t >> 4) * 4;
                const float len = lds_len[e];
                float rad[8];
                #pragma unroll
                for (int r = 0; r < 8; ++r) {
                    const float d = len - 0.7142857143f * (float)r;
                    rad[r] = __expf(-0.5f * d * d);
                }
                float4v hv;
                #pragma unroll
                for (int i = 0; i < 4; ++i) {
                    const float4v wA = *(const float4v*)(&lds_w1t[(c0 + i) * 8]);
                    const float4v wB = *(const float4v*)(&lds_w1t[(c0 + i) * 8 + 4]);
                    float s = rad[0] * wA[0] + rad[1] * wA[1] + rad[2] * wA[2] + rad[3] * wA[3]
                            + rad[4] * wB[0] + rad[5] * wB[1] + rad[6] * wB[2] + rad[7] * wB[3];
                    s *= 0.3535533906f;
                    hv[i] = s / (1.f + __expf(-s));
                }
                *(float4v*)(&lds_h[e * 72 + c0]) = hv;
            }
        }
        __syncthreads();

        // ---- phase 3: A fragments (f16 hi/lo from fp32 LDS; shared by all waves) ----
        const float* hrow = &lds_h[qm * 72];
        const float4v fa = *(const float4v*)(hrow + quad * 8);
        const float4v fb = *(const float4v*)(hrow + quad * 8 + 4);
        const float4v fc = *(const float4v*)(hrow + 32 + quad * 8);
        const float4v fd = *(const float4v*)(hrow + 32 + quad * 8 + 4);
        half8 ah0, al0, ah1, al1;
        #pragma unroll
        for (int j = 0; j < 4; ++j) {
            _Float16 hh;
            hh = (_Float16)fa[j]; ah0[j]     = hh; al0[j]     = (_Float16)(fa[j] - (float)hh);
            hh = (_Float16)fb[j]; ah0[4 + j] = hh; al0[4 + j] = (_Float16)(fb[j] - (float)hh);
            hh = (_Float16)fc[j]; ah1[j]     = hh; al1[j]     = (_Float16)(fc[j] - (float)hh);
            hh = (_Float16)fd[j]; ah1[4 + j] = hh; al1[4 + j] = (_Float16)(fd[j] - (float)hh);
        }

        // ---- u-streamed MFMA + immediate contraction into partials ----
        float sp[4]  = {0.f, 0.f, 0.f, 0.f};   // progs 0..2
        float sp3[3][4];                        // prog 3 (k-resolved)
        #pragma unroll
        for (int k = 0; k < 3; ++k)
            #pragma unroll
            for (int r = 0; r < 4; ++r) sp3[k][r] = 0.f;

        #pragma unroll
        for (int up = 0; up < 8; ++up) {
            const int u = uh * 8 + up;
            float4v acc = (float4v){0.f, 0.f, 0.f, 0.f};
            acc = __builtin_amdgcn_mfma_f32_16x16x32_f16(ah0, bfr[up][0], acc, 0, 0, 0);
            acc = __builtin_amdgcn_mfma_f32_16x16x32_f16(al0, bfr[up][0], acc, 0, 0, 0);
            acc = __builtin_amdgcn_mfma_f32_16x16x32_f16(ah1, bfr[up][1], acc, 0, 0, 0);
            acc = __builtin_amdgcn_mfma_f32_16x16x32_f16(al1, bfr[up][1], acc, 0, 0, 0);
            // C layout: col v = qm, row e = quad*4 + r
            if (prog == 3) {
                #pragma unroll
                for (int r = 0; r < 4; ++r) {
                    const int er = quad * 4 + r;
                    #pragma unroll
                    for (int k = 0; k < 3; ++k)
                        sp3[k][r] = fmaf(lds_xt[(er * 3 + k) * 20 + u], acc[r], sp3[k][r]);
                }
            } else if (prog == 1) {
                #pragma unroll
                for (int r = 0; r < 4; ++r)
                    sp[r] = fmaf(lds_b1[(quad * 4 + r) * 68 + u], acc[r], sp[r]);
            } else {  // progs 0, 2: coefficient = xj0[e][u]
                #pragma unroll
                for (int r = 0; r < 4; ++r)
                    sp[r] = fmaf(lds_xj[(quad * 4 + r) * 68 + u], acc[r], sp[r]);
            }
        }

        // ---- write partials to exchange (fp32, padded, plain stores) ----
        if (prog == 3) {
            float* xb = &lds_xch[6 * 272 + uh * 816];
            #pragma unroll
            for (int r = 0; r < 4; ++r) {
                const int er = quad * 4 + r;
                #pragma unroll
                for (int k = 0; k < 3; ++k)
                    xb[er * 51 + qm * 3 + k] = sp3[k][r];
            }
        } else {
            float* xb = &lds_xch[w * 272];
            #pragma unroll
            for (int r = 0; r < 4; ++r)
                xb[(quad * 4 + r) * 17 + qm] = sp[r];
        }
        __syncthreads();

        // ---- combine: 2 output elems per thread, ONE atomic each ----
        #pragma unroll
        for (int i = 0; i < 2; ++i) {
            const int idx = t + 512 * i;          // 1024 = 16 edges x 64 elems
            const int e = idx >> 6, j = idx & 63;
            float val;
            if (j < 16) {
                // m0[v=j] = sh0*(prog0 halves) + (prog1 halves, INV_SQRT3 in bfr)
                const float s0 = lds_xch[0 * 272 + e * 17 + j] + lds_xch[1 * 272 + e * 17 + j];
                const float s1 = lds_xch[2 * 272 + e * 17 + j] + lds_xch[3 * 272 + e * 17 + j];
                val = fmaf(s0, lds_sh[e * 4], s1);
            } else {
                const int q = j - 16, v = q / 3, k = q - 3 * v;
                // m1[v][k] = sh1[k]*(prog2 halves) + sh0*(prog3 halves)
                const float s2 = lds_xch[4 * 272 + e * 17 + v] + lds_xch[5 * 272 + e * 17 + v];
                const float s3 = lds_xch[6 * 272 + e * 51 + q] + lds_xch[6 * 272 + 816 + e * 51 + q];
                val = s2 * lds_sh[e * 4 + 1 + k] + s3 * lds_sh[e * 4];
            }
            atomicAdd(out + lds_dst[e] * 64 + j, val);
        }
        // next-iteration top barrier orders these LDS reads before re-staging
    }
}

extern "C" void kernel_launch(void* const* d_in, const int* in_sizes, int n_in,
                              void* d_out, int out_size, void* d_ws, size_t ws_size,
                              hipStream_t stream) {
    const float* x           = (const float*)d_in[0];
    const float* edge_attr   = (const float*)d_in[1];
    const float* edge_length = (const float*)d_in[2];
    const int*   edge_src    = (const int*)d_in[3];
    const int*   edge_dst    = (const int*)d_in[4];
    const float* W1          = (const float*)d_in[5];
    const float* W2          = (const float*)d_in[6];
    const float* L0          = (const float*)d_in[7];
    const float* L1          = (const float*)d_in[8];
    float* out = (float*)d_out;

    sc_kernel<<<(N_NODES * 64 + 255) / 256, 256, 0, stream>>>(x, L0, L1, out);
    edge_kernel<<<NBLK, 512, 0, stream>>>(
        x, edge_attr, edge_length, edge_src, edge_dst, W1, W2, out);
}

// Round 7
// 262.406 us; speedup vs baseline: 1.3030x; 1.1497x over previous
//
#include <hip/hip_runtime.h>

// Problem constants
#define N_NODES 25000
#define N_EDGES 200000
// MUL=16, NUM_RADIAL=8, HIDDEN=64, WNUMEL=1024
// PATH_ALPHA=1/sqrt(32), INV_SQRT3=1/sqrt(3), scales folded into B-fragments.

constexpr int ET = 16;      // edges per tile
constexpr int NT = 10;      // tiles per block
constexpr int NBLK = 1250;  // 1250*10*16 = 200000 edges exactly

typedef __attribute__((ext_vector_type(8))) _Float16 half8;  // 8 f16 (4 VGPR)
typedef __attribute__((ext_vector_type(4))) float float4v;   // 4 fp32
typedef __attribute__((ext_vector_type(2))) float float2v;   // 2 fp32

__device__ __forceinline__ half8 h8s(half8 a, _Float16 c) { return a * c; }  // v_pk_mul_f16 x4

// ---------------- self-connection: out = sc (full overwrite) ----------------
__global__ __launch_bounds__(256) void sc_kernel(const float* __restrict__ x,
                                                 const float* __restrict__ L0,
                                                 const float* __restrict__ L1,
                                                 float* __restrict__ out) {
    __shared__ float l0[256], l1[256];
    __shared__ float xs[4][68];
    const int t = threadIdx.x;
    l0[t] = L0[t];
    l1[t] = L1[t];
    const int g = t >> 6, j = t & 63;
    const int n = blockIdx.x * 4 + g;          // 6250 blocks x 4 nodes
    xs[g][j] = x[n * 64 + j];                  // coalesced
    __syncthreads();
    float s = 0.f;
    if (j < 16) {
        #pragma unroll
        for (int u = 0; u < 16; ++u) s = fmaf(xs[g][u], l0[u * 16 + j], s);
    } else {
        const int q = j - 16, v = q / 3, k = q - 3 * v;
        #pragma unroll
        for (int u = 0; u < 16; ++u) s = fmaf(xs[g][16 + 3 * u + k], l1[u * 16 + v], s);
    }
    out[n * 64 + j] = 0.25f * s;   // 1/sqrt(MUL)
}

// ---------------- edge kernel: contraction folded into MFMA ----------------
// 512 threads, 8 waves. Wave w: prog = w>>1, uh = w&1 (u in [uh*8, uh*8+8)).
// Per u, the A fragment (h, f16 hi/lo) is scaled by coef[e][u] (f16, pk_mul)
// and fed to MFMA; the chained accumulator directly yields the per-edge term:
//   C[e][v] = sum_u coef[e][u] * sum_c h[e][c]*W2[c][u*16+v]*scale
// Coef planes: 0: xj0*sh0 (p0) | 1: b1 (p1) | 2: xj0 (p2) | 3+k: xj1[.,k]*sh0 (p3)
__global__ __launch_bounds__(512, 4) void edge_kernel(
    const float* __restrict__ x, const float* __restrict__ edge_attr,
    const float* __restrict__ edge_length, const int* __restrict__ edge_src,
    const int* __restrict__ edge_dst, const float* __restrict__ W1,
    const float* __restrict__ W2, float* __restrict__ out) {

    const int t = threadIdx.x;
    const int w = t >> 6;             // wave id 0..7
    const int prog = w >> 1;          // which 16x16-block family of w2
    const int uh = w & 1;             // u-half
    const int qm = t & 15;            // MFMA m/n index (edge for A/C, v for B)
    const int quad = (t >> 4) & 3;    // lane quad within wave

    __shared__ __attribute__((aligned(16))) float lds_h[16 * 72];   // fp32 h, stride 72
    __shared__ __attribute__((aligned(16))) float lds_xj[16 * 68];  // gathered x[src], stride 68
    __shared__ __attribute__((aligned(16))) float lds_cf[6 * 272];  // coef planes [pl][e*17+u]
    __shared__ __attribute__((aligned(16))) float lds_xch[12 * 272];// term exchange [pl][e*17+v]
    __shared__ __attribute__((aligned(16))) float lds_w1t[64 * 8];  // W1^T [c][r]
    __shared__ __attribute__((aligned(16))) float lds_sh[16 * 4];
    __shared__ __attribute__((aligned(16))) float lds_len[16];
    __shared__ __attribute__((aligned(16))) int   lds_dst[16];

    // ---- persistent B fragments: W2 block `prog`, u-half `uh`, pre-scaled f16 ----
    // B-frag layout (16x16x32): lane holds B[k = kf*32 + quad*8 + j][n = qm]
    half8 bfr[8][2];
    {
        float scale = 0.0220970869f;                  // (1/sqrt(64)) * (1/sqrt(32))
        if (prog == 1) scale *= 0.5773502692f;        // INV_SQRT3 folded
        const int kr = quad * 8;
        #pragma unroll
        for (int up = 0; up < 8; ++up) {
            const int col = prog * 256 + (uh * 8 + up) * 16 + qm;
            #pragma unroll
            for (int kf = 0; kf < 2; ++kf) {
                half8 f;
                #pragma unroll
                for (int j = 0; j < 8; ++j) {
                    const int k = kf * 32 + kr + j;
                    f[j] = (_Float16)(W2[k * 1024 + col] * scale);
                }
                bfr[up][kf] = f;
            }
        }
    }
    // W1 -> LDS transposed [c][r]
    if (t < 512) {
        const int r = t >> 6, c = t & 63;
        lds_w1t[c * 8 + r] = W1[t];
    }

    for (int tl = 0; tl < NT; ++tl) {
        const int e0 = (blockIdx.x * NT + tl) * ET;
        __syncthreads();   // orders prev-tile combine reads before re-staging

        // ---- phase 1: meta + xj gather (all 8 waves, 2 edges each) ----
        if (t < 16) {
            lds_dst[t] = edge_dst[e0 + t];
            lds_len[t] = edge_length[e0 + t];
            const float4v ea = *(const float4v*)(edge_attr + 4 * (e0 + t));
            lds_sh[t * 4 + 0] = ea[0]; lds_sh[t * 4 + 1] = ea[1];
            lds_sh[t * 4 + 2] = ea[2]; lds_sh[t * 4 + 3] = ea[3];
        }
        {
            const int l = t & 63;
            const int e_loc = w * 2 + (l >> 5);           // half-wave-uniform src
            const int src = edge_src[e0 + e_loc];
            const int c2 = (l & 31) * 2;
            *(float2v*)(&lds_xj[e_loc * 68 + c2]) = *(const float2v*)(x + src * 64 + c2);
        }
        __syncthreads();

        if (t < 256) {
            // ---- phase 2a: coef planes ----
            const int e = t & 15, u = t >> 4;
            const float sh0 = lds_sh[e * 4];
            const float s1x = lds_sh[e * 4 + 1];
            const float s1y = lds_sh[e * 4 + 2];
            const float s1z = lds_sh[e * 4 + 3];
            const float xj0v = lds_xj[e * 68 + u];
            const float x0 = lds_xj[e * 68 + 16 + 3 * u];
            const float x1 = lds_xj[e * 68 + 17 + 3 * u];
            const float x2 = lds_xj[e * 68 + 18 + 3 * u];
            lds_cf[0 * 272 + e * 17 + u] = xj0v * sh0;
            lds_cf[1 * 272 + e * 17 + u] = fmaf(x0, s1x, fmaf(x1, s1y, x2 * s1z));
            lds_cf[2 * 272 + e * 17 + u] = xj0v;
            lds_cf[3 * 272 + e * 17 + u] = x0 * sh0;
            lds_cf[4 * 272 + e * 17 + u] = x1 * sh0;
            lds_cf[5 * 272 + e * 17 + u] = x2 * sh0;
            // ---- phase 2b: h = silu(radial @ W1 / sqrt(8)) -> fp32 LDS ----
            const int c0 = u * 4;
            const float len = lds_len[e];
            float rad[8];
            #pragma unroll
            for (int r = 0; r < 8; ++r) {
                const float d = len - 0.7142857143f * (float)r;
                rad[r] = __expf(-0.5f * d * d);
            }
            float4v hv;
            #pragma unroll
            for (int i = 0; i < 4; ++i) {
                const float4v wA = *(const float4v*)(&lds_w1t[(c0 + i) * 8]);
                const float4v wB = *(const float4v*)(&lds_w1t[(c0 + i) * 8 + 4]);
                float s = rad[0] * wA[0] + rad[1] * wA[1] + rad[2] * wA[2] + rad[3] * wA[3]
                        + rad[4] * wB[0] + rad[5] * wB[1] + rad[6] * wB[2] + rad[7] * wB[3];
                s *= 0.3535533906f;
                hv[i] = s / (1.f + __expf(-s));
            }
            *(float4v*)(&lds_h[e * 72 + c0]) = hv;
        }
        __syncthreads();

        // ---- phase 3: A fragments (f16 hi/lo from fp32 LDS) ----
        // lane holds h[m=qm][k = half*32 + quad*8 + j]
        const float* hrow = &lds_h[qm * 72];
        const float4v fa = *(const float4v*)(hrow + quad * 8);
        const float4v fb = *(const float4v*)(hrow + quad * 8 + 4);
        const float4v fc = *(const float4v*)(hrow + 32 + quad * 8);
        const float4v fd = *(const float4v*)(hrow + 32 + quad * 8 + 4);
        half8 ah0, al0, ah1, al1;
        #pragma unroll
        for (int j = 0; j < 4; ++j) {
            _Float16 hh;
            hh = (_Float16)fa[j]; ah0[j]     = hh; al0[j]     = (_Float16)(fa[j] - (float)hh);
            hh = (_Float16)fb[j]; ah0[4 + j] = hh; al0[4 + j] = (_Float16)(fb[j] - (float)hh);
            hh = (_Float16)fc[j]; ah1[j]     = hh; al1[j]     = (_Float16)(fc[j] - (float)hh);
            hh = (_Float16)fd[j]; ah1[4 + j] = hh; al1[4 + j] = (_Float16)(fd[j] - (float)hh);
        }

        // ---- MFMA with per-u coef-scaled A; C = final per-edge term ----
        if (prog < 3) {
            float4v acc = (float4v){0.f, 0.f, 0.f, 0.f};
            #pragma unroll
            for (int up = 0; up < 8; ++up) {
                const int u = uh * 8 + up;
                const _Float16 c = (_Float16)lds_cf[prog * 272 + qm * 17 + u];
                acc = __builtin_amdgcn_mfma_f32_16x16x32_f16(h8s(ah0, c), bfr[up][0], acc, 0, 0, 0);
                acc = __builtin_amdgcn_mfma_f32_16x16x32_f16(h8s(al0, c), bfr[up][0], acc, 0, 0, 0);
                acc = __builtin_amdgcn_mfma_f32_16x16x32_f16(h8s(ah1, c), bfr[up][1], acc, 0, 0, 0);
                acc = __builtin_amdgcn_mfma_f32_16x16x32_f16(h8s(al1, c), bfr[up][1], acc, 0, 0, 0);
            }
            // C layout: col v = qm, row e = quad*4 + r
            float* xb = &lds_xch[w * 272];
            #pragma unroll
            for (int r = 0; r < 4; ++r) xb[(quad * 4 + r) * 17 + qm] = acc[r];
        } else {
            float4v a3[3];
            #pragma unroll
            for (int k = 0; k < 3; ++k) a3[k] = (float4v){0.f, 0.f, 0.f, 0.f};
            #pragma unroll
            for (int up = 0; up < 8; ++up) {
                const int u = uh * 8 + up;
                #pragma unroll
                for (int k = 0; k < 3; ++k) {
                    const _Float16 c = (_Float16)lds_cf[(3 + k) * 272 + qm * 17 + u];
                    a3[k] = __builtin_amdgcn_mfma_f32_16x16x32_f16(h8s(ah0, c), bfr[up][0], a3[k], 0, 0, 0);
                    a3[k] = __builtin_amdgcn_mfma_f32_16x16x32_f16(h8s(al0, c), bfr[up][0], a3[k], 0, 0, 0);
                    a3[k] = __builtin_amdgcn_mfma_f32_16x16x32_f16(h8s(ah1, c), bfr[up][1], a3[k], 0, 0, 0);
                    a3[k] = __builtin_amdgcn_mfma_f32_16x16x32_f16(h8s(al1, c), bfr[up][1], a3[k], 0, 0, 0);
                }
            }
            #pragma unroll
            for (int k = 0; k < 3; ++k) {
                float* xb = &lds_xch[(6 + uh * 3 + k) * 272];
                #pragma unroll
                for (int r = 0; r < 4; ++r) xb[(quad * 4 + r) * 17 + qm] = a3[k][r];
            }
        }
        __syncthreads();

        // ---- combine: 2 output elems per thread, ONE atomic each ----
        #pragma unroll
        for (int i = 0; i < 2; ++i) {
            const int idx = t + 512 * i;          // 1024 = 16 edges x 64 elems
            const int e = idx >> 6, j = idx & 63;
            float val;
            if (j < 16) {
                // m0[v=j]: p0 (sh0 in coef) + p1 (INV_SQRT3 in bfr), both uh halves
                val = (lds_xch[0 * 272 + e * 17 + j] + lds_xch[1 * 272 + e * 17 + j])
                    + (lds_xch[2 * 272 + e * 17 + j] + lds_xch[3 * 272 + e * 17 + j]);
            } else {
                const int q = j - 16, v = q / 3, k = q - 3 * v;
                // m1[v][k] = sh1[k]*p2[v] + p3k[v]  (sh0 folded into p3 coef)
                const float s2 = lds_xch[4 * 272 + e * 17 + v] + lds_xch[5 * 272 + e * 17 + v];
                const float s3 = lds_xch[(6 + k) * 272 + e * 17 + v]
                               + lds_xch[(9 + k) * 272 + e * 17 + v];
                val = fmaf(s2, lds_sh[e * 4 + 1 + k], s3);
            }
            atomicAdd(out + lds_dst[e] * 64 + j, val);
        }
        // next-iteration top barrier orders these LDS reads before re-staging
    }
}

extern "C" void kernel_launch(void* const* d_in, const int* in_sizes, int n_in,
                              void* d_out, int out_size, void* d_ws, size_t ws_size,
                              hipStream_t stream) {
    const float* x           = (const float*)d_in[0];
    const float* edge_attr   = (const float*)d_in[1];
    const float* edge_length = (const float*)d_in[2];
    const int*   edge_src    = (const int*)d_in[3];
    const int*   edge_dst    = (const int*)d_in[4];
    const float* W1          = (const float*)d_in[5];
    const float* W2          = (const float*)d_in[6];
    const float* L0          = (const float*)d_in[7];
    const float* L1          = (const float*)d_in[8];
    float* out = (float*)d_out;

    sc_kernel<<<N_NODES / 4, 256, 0, stream>>>(x, L0, L1, out);
    edge_kernel<<<NBLK, 512, 0, stream>>>(
        x, edge_attr, edge_length, edge_src, edge_dst, W1, W2, out);
}